// Round 8
// baseline (401.813 us; speedup 1.0000x reference)
//
#include <hip/hip_runtime.h>

#define NS_N 10000
#define NM_N 50000
#define HD 128
#define E1_N 600000
#define E2_N 400000
#define L_N 200000

#define RSZ 4096
#define NB_A 13
#define NB_S 3
#define NB_TOT 42
#define CHK 16
#define NCB (NB_TOT * CHK)      // 672 count/place blocks
#define NCONV 1932              // conv blocks
#define NFIN 196                // finalize blocks (50176 threads)

typedef short bf16x8 __attribute__((ext_vector_type(8)));
typedef float f32x4 __attribute__((ext_vector_type(4)));

__device__ inline float bf2f(unsigned int h) {
    union { unsigned int u; float f; } c; c.u = h << 16; return c.f;
}
__device__ inline unsigned short f2bf(float f) {
    union { float f; unsigned int u; } c; c.f = f;
    return (unsigned short)((c.u + 0x7fffu + ((c.u >> 16) & 1u)) >> 16);
}

// range table:  [0,13): csrA key=e1d payl=e1s (NM) | [13,16): csrS key=e1s payl=e1d (NS)
//               [16,29): csr0 key=e2d payl=e2s (NM) | [29,42): csr1 key=e2s payl=e2d (NM)

// ---------------- pass 1 (+ fp32->bf16 conversions fused as extra blocks) ----------------

__global__ __launch_bounds__(256) void count_conv(
        const int* __restrict__ e1s, const int* __restrict__ e1d,
        const int* __restrict__ e2s, const int* __restrict__ e2d,
        int* __restrict__ subcnt, int* __restrict__ chunkTot,
        const float* __restrict__ emb_s, const float* __restrict__ emb_m,
        const float* __restrict__ sage_Wl, const float* __restrict__ sage_Wr,
        const float* __restrict__ gcn_W,
        unsigned short* __restrict__ emb_s16, unsigned short* __restrict__ emb_m16,
        unsigned short* __restrict__ Wt) {
    __shared__ int hist[RSZ];
    __shared__ int wred[4];
    int b = blockIdx.x, tid = threadIdx.x;
    if (b < NCB) {
        int rb = b / CHK, c = b % CHK;
        const int* keys; int ne; int nnode; int r0;
        if (rb < NB_A)             { keys = e1d; ne = E1_N; nnode = NM_N; r0 = rb * RSZ; }
        else if (rb < NB_A + NB_S) { keys = e1s; ne = E1_N; nnode = NS_N; r0 = (rb - NB_A) * RSZ; }
        else if (rb < 29)          { keys = e2d; ne = E2_N; nnode = NM_N; r0 = (rb - 16) * RSZ; }
        else                       { keys = e2s; ne = E2_N; nnode = NM_N; r0 = (rb - 29) * RSZ; }
        for (int i = tid; i < RSZ; i += 256) hist[i] = 0;
        __syncthreads();
        int hi = nnode - r0; if (hi > RSZ) hi = RSZ;
        const int4* k4 = (const int4*)keys;
        int ne4 = ne >> 2;
        int per = (ne4 + CHK - 1) / CHK;
        int i0 = c * per, i1 = i0 + per; if (i1 > ne4) i1 = ne4;
        for (int i = i0 + tid; i < i1; i += 256) {
            int4 v = k4[i];
            int x;
            x = v.x - r0; if ((unsigned)x < (unsigned)hi) atomicAdd(&hist[x], 1);
            x = v.y - r0; if ((unsigned)x < (unsigned)hi) atomicAdd(&hist[x], 1);
            x = v.z - r0; if ((unsigned)x < (unsigned)hi) atomicAdd(&hist[x], 1);
            x = v.w - r0; if ((unsigned)x < (unsigned)hi) atomicAdd(&hist[x], 1);
        }
        __syncthreads();
        int* sc = subcnt + (size_t)b * RSZ;
        int loc = 0;
        for (int i = tid; i < RSZ; i += 256) { int h = hist[i]; sc[i] = h; loc += h; }
        #pragma unroll
        for (int o = 32; o; o >>= 1) loc += __shfl_xor(loc, o);
        if ((tid & 63) == 0) wred[tid >> 6] = loc;
        __syncthreads();
        if (tid == 0) chunkTot[b] = wred[0] + wred[1] + wred[2] + wred[3];
        return;
    }
    int cb = b - NCB;
    if (cb < 1920) {
        const float* src; unsigned short* dst; int n8; int i; int stride;
        if (cb < 1600) { src = emb_m; dst = emb_m16; n8 = NM_N * HD / 8; i = cb * 256 + tid; stride = 1600 * 256; }
        else { src = emb_s; dst = emb_s16; n8 = NS_N * HD / 8; i = (cb - 1600) * 256 + tid; stride = 320 * 256; }
        for (; i < n8; i += stride) {
            float4 v0 = ((const float4*)src)[(size_t)i * 2];
            float4 v1 = ((const float4*)src)[(size_t)i * 2 + 1];
            uint4 r;
            r.x = (unsigned int)f2bf(v0.x) | ((unsigned int)f2bf(v0.y) << 16);
            r.y = (unsigned int)f2bf(v0.z) | ((unsigned int)f2bf(v0.w) << 16);
            r.z = (unsigned int)f2bf(v1.x) | ((unsigned int)f2bf(v1.y) << 16);
            r.w = (unsigned int)f2bf(v1.z) | ((unsigned int)f2bf(v1.w) << 16);
            ((uint4*)dst)[i] = r;
        }
        return;
    }
    int o = cb - 1920;
    int l = o / 6, m = o % 6;
    const float* src;
    switch (m) {
        case 0: src = sage_Wl + (size_t)(l * 2 + 0) * HD * HD; break;
        case 1: src = sage_Wr + (size_t)(l * 2 + 0) * HD * HD; break;
        case 2: src = gcn_W + (size_t)(l * 2 + 0) * HD * HD; break;
        case 3: src = gcn_W + (size_t)(l * 2 + 1) * HD * HD; break;
        case 4: src = sage_Wl + (size_t)(l * 2 + 1) * HD * HD; break;
        default: src = sage_Wr + (size_t)(l * 2 + 1) * HD * HD; break;
    }
    for (int it = 0; it < 64; it++) {
        int f = it * 256 + tid;      // f = n*128 + k
        int n = f >> 7, k = f & 127;
        Wt[(size_t)o * 16384 + f] = f2bf(src[k * 128 + n]);
    }
}

// ---------------- pass 2 ----------------

__global__ void scan_ranges2(const int* __restrict__ chunkTot, int* __restrict__ rangeBase) {
    int t = threadIdx.x;
    if (t >= 4) return;
    const int s0[5] = {0, 13, 16, 29, 42};
    int acc = 0;
    for (int r = s0[t]; r < s0[t + 1]; r++) {
        rangeBase[r] = acc;
        int tot = 0;
        for (int c = 0; c < CHK; c++) tot += chunkTot[r * CHK + c];
        acc += tot;
    }
}

// ---------------- pass 3 ----------------

__global__ __launch_bounds__(1024) void reduce_scan(
        const int* __restrict__ rangeBase,
        int* __restrict__ subcnt,
        int* cntM, int* cntS, int* cnt0, int* cnt1,
        int* offM, int* offS, int* off0, int* off1) {
    __shared__ int wsum[16];
    int rb = blockIdx.x, tid = threadIdx.x;
    int lane = tid & 63, w = tid >> 6;
    int* cnt; int* off; int nnode; int r0;
    if (rb < NB_A)             { cnt = cntM; off = offM; nnode = NM_N; r0 = rb * RSZ; }
    else if (rb < NB_A + NB_S) { cnt = cntS; off = offS; nnode = NS_N; r0 = (rb - NB_A) * RSZ; }
    else if (rb < 29)          { cnt = cnt0; off = off0; nnode = NM_N; r0 = (rb - 16) * RSZ; }
    else                       { cnt = cnt1; off = off1; nnode = NM_N; r0 = (rb - 29) * RSZ; }
    int hi = nnode - r0; if (hi > RSZ) hi = RSZ;
    int base = rangeBase[rb];
    int* sc0 = subcnt + (size_t)(rb * CHK) * RSZ;
    int cv[4]; int s = 0;
    #pragma unroll
    for (int q = 0; q < 4; q++) {
        int idx = tid * 4 + q;
        int t = 0;
        if (idx < hi)
            for (int c = 0; c < CHK; c++) t += sc0[(size_t)c * RSZ + idx];
        cv[q] = t; s += t;
    }
    int x = s;
    #pragma unroll
    for (int d = 1; d < 64; d <<= 1) { int y = __shfl_up(x, d); if (lane >= d) x += y; }
    if (lane == 63) wsum[w] = x;
    __syncthreads();
    if (w == 0 && lane < 16) {
        int y = wsum[lane];
        #pragma unroll
        for (int d = 1; d < 16; d <<= 1) { int z = __shfl_up(y, d); if (lane >= d) y += z; }
        wsum[lane] = y;
    }
    __syncthreads();
    int ebase = base + ((w > 0) ? wsum[w - 1] : 0) + (x - s);
    #pragma unroll
    for (int q = 0; q < 4; q++) {
        int idx = tid * 4 + q;
        if (idx < hi) {
            off[r0 + idx] = ebase;
            cnt[r0 + idx] = cv[q];
            int running = ebase;
            for (int c = 0; c < CHK; c++) {
                size_t a = (size_t)c * RSZ + idx;
                int tmp = sc0[a];
                sc0[a] = running;
                running += tmp;
            }
        }
        ebase += cv[q];
    }
}

// ---------------- pass 4 (+ finalize fused as extra blocks) ----------------

__global__ __launch_bounds__(256) void place_fin(
        const int* __restrict__ e1s, const int* __restrict__ e1d,
        const int* __restrict__ e2s, const int* __restrict__ e2d,
        const int* __restrict__ subcnt,
        int* csrA, int* csrS, int* csr0, int* csr1,
        const int* __restrict__ cntM, const int* __restrict__ cntS,
        const int* __restrict__ cnt0, const int* __restrict__ cnt1,
        float* invCntM, float* invCntS,
        float* dinv0, float* inv0, float* dinv1, float* inv1,
        const float* __restrict__ sage_bl, const float* __restrict__ gcn_b,
        float* bsum) {
    __shared__ int cur[RSZ];
    int b = blockIdx.x, tid = threadIdx.x;
    if (b >= NCB) {
        int i = (b - NCB) * 256 + tid;
        if (i < NM_N) {
            int c = cntM[i];
            invCntM[i] = 1.0f / (float)(c > 1 ? c : 1);
            float d0 = (float)cnt0[i] + 1.0f;
            dinv0[i] = 1.0f / sqrtf(d0);
            inv0[i] = 1.0f / d0;
            float d1 = (float)cnt1[i] + 1.0f;
            dinv1[i] = 1.0f / sqrtf(d1);
            inv1[i] = 1.0f / d1;
        }
        if (i < NS_N) {
            int c = cntS[i];
            invCntS[i] = 1.0f / (float)(c > 1 ? c : 1);
        }
        if (i < 256) {
            int l = i >> 7, c = i & 127;
            bsum[i] = sage_bl[(l * 2 + 0) * HD + c] + gcn_b[(l * 2 + 0) * HD + c] + gcn_b[(l * 2 + 1) * HD + c];
        }
        return;
    }
    int rb = b / CHK, c = b % CHK;
    const int* keys; const int* payl; int ne; int* csr; int nnode; int r0;
    if (rb < NB_A)             { keys = e1d; payl = e1s; ne = E1_N; csr = csrA; nnode = NM_N; r0 = rb * RSZ; }
    else if (rb < NB_A + NB_S) { keys = e1s; payl = e1d; ne = E1_N; csr = csrS; nnode = NS_N; r0 = (rb - NB_A) * RSZ; }
    else if (rb < 29)          { keys = e2d; payl = e2s; ne = E2_N; csr = csr0; nnode = NM_N; r0 = (rb - 16) * RSZ; }
    else                       { keys = e2s; payl = e2d; ne = E2_N; csr = csr1; nnode = NM_N; r0 = (rb - 29) * RSZ; }
    int hi = nnode - r0; if (hi > RSZ) hi = RSZ;
    const int* sc = subcnt + (size_t)b * RSZ;
    for (int i = tid; i < hi; i += 256) cur[i] = sc[i];
    __syncthreads();
    const int4* k4 = (const int4*)keys;
    const int4* p4 = (const int4*)payl;
    int ne4 = ne >> 2;
    int per = (ne4 + CHK - 1) / CHK;
    int i0 = c * per, i1 = i0 + per; if (i1 > ne4) i1 = ne4;
    for (int i = i0 + tid; i < i1; i += 256) {
        int4 k = k4[i]; int4 p = p4[i];
        int xx;
        xx = k.x - r0; if ((unsigned)xx < (unsigned)hi) csr[atomicAdd(&cur[xx], 1)] = p.x;
        xx = k.y - r0; if ((unsigned)xx < (unsigned)hi) csr[atomicAdd(&cur[xx], 1)] = p.y;
        xx = k.z - r0; if ((unsigned)xx < (unsigned)hi) csr[atomicAdd(&cur[xx], 1)] = p.z;
        xx = k.w - r0; if ((unsigned)xx < (unsigned)hi) csr[atomicAdd(&cur[xx], 1)] = p.w;
    }
}

// ---------------- fused gathers (bf16 rows, fp32 accum, 16 lanes/row, 4x MLP) ----------------

#define ACC8(v) do { \
    a0 += bf2f((v).x & 0xffffu); a1 += bf2f((v).x >> 16); \
    a2 += bf2f((v).y & 0xffffu); a3 += bf2f((v).y >> 16); \
    a4 += bf2f((v).z & 0xffffu); a5 += bf2f((v).z >> 16); \
    a6 += bf2f((v).w & 0xffffu); a7 += bf2f((v).w >> 16); } while (0)

#define ACC8C(v, cf) do { \
    a0 += (cf) * bf2f((v).x & 0xffffu); a1 += (cf) * bf2f((v).x >> 16); \
    a2 += (cf) * bf2f((v).y & 0xffffu); a3 += (cf) * bf2f((v).y >> 16); \
    a4 += (cf) * bf2f((v).z & 0xffffu); a5 += (cf) * bf2f((v).z >> 16); \
    a6 += (cf) * bf2f((v).w & 0xffffu); a7 += (cf) * bf2f((v).w >> 16); } while (0)

__device__ inline void gath_mean(const unsigned short* __restrict__ x,
                                 const int* __restrict__ csr, const int* __restrict__ off,
                                 const int* __restrict__ cnt, const float* __restrict__ invc,
                                 unsigned short* __restrict__ out, int row, int lane) {
    int o = off[row], n = cnt[row];
    float a0=0,a1=0,a2=0,a3=0,a4=0,a5=0,a6=0,a7=0;
    int j = 0;
    for (; j + 4 <= n; j += 4) {
        int s0 = csr[o + j], s1 = csr[o + j + 1], s2 = csr[o + j + 2], s3 = csr[o + j + 3];
        uint4 v0 = *(const uint4*)(x + (size_t)s0 * 128 + lane * 8);
        uint4 v1 = *(const uint4*)(x + (size_t)s1 * 128 + lane * 8);
        uint4 v2 = *(const uint4*)(x + (size_t)s2 * 128 + lane * 8);
        uint4 v3 = *(const uint4*)(x + (size_t)s3 * 128 + lane * 8);
        ACC8(v0); ACC8(v1); ACC8(v2); ACC8(v3);
    }
    for (; j < n; j++) {
        int s0 = csr[o + j];
        uint4 v = *(const uint4*)(x + (size_t)s0 * 128 + lane * 8);
        ACC8(v);
    }
    float sc = invc[row];
    uint4 r;
    r.x = (unsigned int)f2bf(a0 * sc) | ((unsigned int)f2bf(a1 * sc) << 16);
    r.y = (unsigned int)f2bf(a2 * sc) | ((unsigned int)f2bf(a3 * sc) << 16);
    r.z = (unsigned int)f2bf(a4 * sc) | ((unsigned int)f2bf(a5 * sc) << 16);
    r.w = (unsigned int)f2bf(a6 * sc) | ((unsigned int)f2bf(a7 * sc) << 16);
    *(uint4*)(out + (size_t)row * 128 + lane * 8) = r;
}

__device__ inline void gath_gcn(const unsigned short* __restrict__ x,
                                const int* __restrict__ csr, const int* __restrict__ off,
                                const int* __restrict__ cnt, const float* __restrict__ dinv,
                                const float* __restrict__ invd,
                                unsigned short* __restrict__ out, int row, int lane) {
    int o = off[row], n = cnt[row];
    float a0=0,a1=0,a2=0,a3=0,a4=0,a5=0,a6=0,a7=0;
    int j = 0;
    for (; j + 4 <= n; j += 4) {
        int s0 = csr[o + j], s1 = csr[o + j + 1], s2 = csr[o + j + 2], s3 = csr[o + j + 3];
        float c0 = dinv[s0], c1 = dinv[s1], c2 = dinv[s2], c3 = dinv[s3];
        uint4 v0 = *(const uint4*)(x + (size_t)s0 * 128 + lane * 8);
        uint4 v1 = *(const uint4*)(x + (size_t)s1 * 128 + lane * 8);
        uint4 v2 = *(const uint4*)(x + (size_t)s2 * 128 + lane * 8);
        uint4 v3 = *(const uint4*)(x + (size_t)s3 * 128 + lane * 8);
        ACC8C(v0, c0); ACC8C(v1, c1); ACC8C(v2, c2); ACC8C(v3, c3);
    }
    for (; j < n; j++) {
        int s0 = csr[o + j];
        float c0 = dinv[s0];
        uint4 v = *(const uint4*)(x + (size_t)s0 * 128 + lane * 8);
        ACC8C(v, c0);
    }
    float dr = dinv[row], iv = invd[row];
    uint4 sv = *(const uint4*)(x + (size_t)row * 128 + lane * 8);
    uint4 r;
    r.x = (unsigned int)f2bf(dr * a0 + iv * bf2f(sv.x & 0xffffu)) |
          ((unsigned int)f2bf(dr * a1 + iv * bf2f(sv.x >> 16)) << 16);
    r.y = (unsigned int)f2bf(dr * a2 + iv * bf2f(sv.y & 0xffffu)) |
          ((unsigned int)f2bf(dr * a3 + iv * bf2f(sv.y >> 16)) << 16);
    r.z = (unsigned int)f2bf(dr * a4 + iv * bf2f(sv.z & 0xffffu)) |
          ((unsigned int)f2bf(dr * a5 + iv * bf2f(sv.z >> 16)) << 16);
    r.w = (unsigned int)f2bf(dr * a6 + iv * bf2f(sv.w & 0xffffu)) |
          ((unsigned int)f2bf(dr * a7 + iv * bf2f(sv.w >> 16)) << 16);
    *(uint4*)(out + (size_t)row * 128 + lane * 8) = r;
}

// sections: [0,3125) A | [3125,3750) Sg | [3750,6875) B0 | [6875,10000) B1
__global__ __launch_bounds__(256) void gather_all(
        const unsigned short* __restrict__ xs, const unsigned short* __restrict__ xm,
        const int* __restrict__ csrA, const int* __restrict__ offM, const int* __restrict__ cntM,
        const float* __restrict__ invCntM,
        const int* __restrict__ csrS, const int* __restrict__ offS, const int* __restrict__ cntS,
        const float* __restrict__ invCntS,
        const int* __restrict__ csr0, const int* __restrict__ off0, const int* __restrict__ cnt0,
        const float* __restrict__ dinv0, const float* __restrict__ inv0,
        const int* __restrict__ csr1, const int* __restrict__ off1, const int* __restrict__ cnt1,
        const float* __restrict__ dinv1, const float* __restrict__ inv1,
        unsigned short* __restrict__ A, unsigned short* __restrict__ Sg,
        unsigned short* __restrict__ B0, unsigned short* __restrict__ B1) {
    int b = blockIdx.x;
    int sub = threadIdx.x >> 4, lane = threadIdx.x & 15;
    if (b < 3125) {
        int row = b * 16 + sub;
        if (row < NM_N) gath_mean(xs, csrA, offM, cntM, invCntM, A, row, lane);
    } else if (b < 3750) {
        int row = (b - 3125) * 16 + sub;
        if (row < NS_N) gath_mean(xm, csrS, offS, cntS, invCntS, Sg, row, lane);
    } else if (b < 6875) {
        int row = (b - 3750) * 16 + sub;
        if (row < NM_N) gath_gcn(xm, csr0, off0, cnt0, dinv0, inv0, B0, row, lane);
    } else {
        int row = (b - 6875) * 16 + sub;
        if (row < NM_N) gath_gcn(xm, csr1, off1, cnt1, dinv1, inv1, B1, row, lane);
    }
}

// ---------------- MFMA GEMM, no LDS: A and W fragments direct from global ----------------

__global__ __launch_bounds__(256) void gemm_all(
        const unsigned short* __restrict__ A, const unsigned short* __restrict__ xm_cur,
        const unsigned short* __restrict__ B0, const unsigned short* __restrict__ B1,
        const unsigned short* __restrict__ Sg, const unsigned short* __restrict__ xs_cur,
        const unsigned short* __restrict__ Wt, const float* __restrict__ bsum,
        const float* __restrict__ sblS,
        unsigned short* __restrict__ xma, unsigned short* __restrict__ xsa, int l) {
    int bb = blockIdx.x;
    const unsigned short *in0, *in1, *in2, *in3, *W;
    const float* bias;
    unsigned short* out;
    int nrows, nseg, r0;
    if (bb < 391) {
        in0 = A; in1 = xm_cur; in2 = B0; in3 = B1;
        W = Wt + (size_t)(l * 6) * 16384;
        bias = bsum + l * 128; out = xma; nrows = NM_N; nseg = 4; r0 = bb * 128;
    } else {
        in0 = Sg; in1 = xs_cur; in2 = nullptr; in3 = nullptr;
        W = Wt + (size_t)(l * 6 + 4) * 16384;
        bias = sblS; out = xsa; nrows = NS_N; nseg = 2; r0 = (bb - 391) * 128;
    }
    int tid = threadIdx.x;
    int wid = tid >> 6, lane = tid & 63;
    int l16 = lane & 15, lhi = lane >> 4;
    int wr_ = (wid >> 1) * 64, wc_ = (wid & 1) * 64;
    const bf16x8 zv = {0, 0, 0, 0, 0, 0, 0, 0};
    f32x4 acc[4][4];
    #pragma unroll
    for (int i = 0; i < 4; i++)
        #pragma unroll
        for (int j = 0; j < 4; j++)
            acc[i][j] = (f32x4){0.f, 0.f, 0.f, 0.f};

    for (int s = 0; s < nseg; s++) {
        const unsigned short* in = (s == 0) ? in0 : (s == 1) ? in1 : (s == 2) ? in2 : in3;
        const unsigned short* Wp = W + (size_t)s * 16384;
        #pragma unroll
        for (int ks = 0; ks < 4; ks++) {
            int kc = ks * 4 + lhi;
            bf16x8 a[4], bfr[4];
            #pragma unroll
            for (int i = 0; i < 4; i++) {
                int gr = r0 + wr_ + i * 16 + l16;
                a[i] = (gr < nrows) ? *(const bf16x8*)(in + (size_t)gr * 128 + kc * 8) : zv;
                int nn = wc_ + i * 16 + l16;
                bfr[i] = *(const bf16x8*)(Wp + (size_t)nn * 128 + kc * 8);
            }
            #pragma unroll
            for (int i = 0; i < 4; i++)
                #pragma unroll
                for (int j = 0; j < 4; j++)
                    acc[i][j] = __builtin_amdgcn_mfma_f32_16x16x32_bf16(a[i], bfr[j], acc[i][j], 0, 0, 0);
        }
    }
    float bs[4];
    #pragma unroll
    for (int j = 0; j < 4; j++) bs[j] = bias[wc_ + j * 16 + l16];
    #pragma unroll
    for (int i = 0; i < 4; i++) {
        int rb = r0 + wr_ + i * 16 + lhi * 4;
        #pragma unroll
        for (int j = 0; j < 4; j++) {
            int cn = wc_ + j * 16 + l16;
            #pragma unroll
            for (int q = 0; q < 4; q++) {
                int r = rb + q;
                if (r < nrows) {
                    float v = acc[i][j][q] + bs[j];
                    out[(size_t)r * 128 + cn] = f2bf(fmaxf(v, 0.f));
                }
            }
        }
    }
}

// ---------------- classifier (16 lanes / pair) ----------------

__global__ __launch_bounds__(256) void classify16(
        const unsigned short* __restrict__ xs_, const unsigned short* __restrict__ xm_,
        const int* __restrict__ lsrc, const int* __restrict__ ldst,
        float* __restrict__ out) {
    int i = blockIdx.x * 16 + (threadIdx.x >> 4);
    if (i >= L_N) return;
    int lane = threadIdx.x & 15;
    int s = lsrc[i], d = ldst[i];
    uint4 a = *(const uint4*)(xs_ + (size_t)s * 128 + lane * 8);
    uint4 b = *(const uint4*)(xm_ + (size_t)d * 128 + lane * 8);
    float p = bf2f(a.x & 0xffffu) * bf2f(b.x & 0xffffu) + bf2f(a.x >> 16) * bf2f(b.x >> 16)
            + bf2f(a.y & 0xffffu) * bf2f(b.y & 0xffffu) + bf2f(a.y >> 16) * bf2f(b.y >> 16)
            + bf2f(a.z & 0xffffu) * bf2f(b.z & 0xffffu) + bf2f(a.z >> 16) * bf2f(b.z >> 16)
            + bf2f(a.w & 0xffffu) * bf2f(b.w & 0xffffu) + bf2f(a.w >> 16) * bf2f(b.w >> 16);
    #pragma unroll
    for (int o = 8; o > 0; o >>= 1) p += __shfl_xor(p, o);
    if (lane == 0) out[i] = p;
}

// ---------------- launch ----------------

extern "C" void kernel_launch(void* const* d_in, const int* in_sizes, int n_in,
                              void* d_out, int out_size, void* d_ws, size_t ws_size,
                              hipStream_t stream) {
    const float* emb_s   = (const float*)d_in[0];
    const float* emb_m   = (const float*)d_in[1];
    const float* sage_Wl = (const float*)d_in[2];
    const float* sage_bl = (const float*)d_in[3];
    const float* sage_Wr = (const float*)d_in[4];
    const float* gcn_W   = (const float*)d_in[5];
    const float* gcn_b   = (const float*)d_in[6];
    const int* e1s = (const int*)d_in[9];
    const int* e1d = (const int*)d_in[10];
    const int* e2s = (const int*)d_in[11];
    const int* e2d = (const int*)d_in[12];
    const int* ls  = (const int*)d_in[13];
    const int* ld  = (const int*)d_in[14];
    float* out = (float*)d_out;

    char* p = (char*)d_ws;
    auto alloc = [&](size_t bytes) -> void* {
        void* r = (void*)p;
        p += (bytes + 255) & ~(size_t)255;
        return r;
    };
    int* cntM = (int*)alloc((size_t)NM_N * 4);
    int* cntS = (int*)alloc((size_t)NS_N * 4);
    int* cnt0 = (int*)alloc((size_t)NM_N * 4);
    int* cnt1 = (int*)alloc((size_t)NM_N * 4);
    int* offM = (int*)alloc((size_t)NM_N * 4);
    int* offS = (int*)alloc((size_t)NS_N * 4);
    int* off0 = (int*)alloc((size_t)NM_N * 4);
    int* off1 = (int*)alloc((size_t)NM_N * 4);
    int* subcnt   = (int*)alloc((size_t)NB_TOT * CHK * RSZ * 4);
    int* chunkTot = (int*)alloc((size_t)NB_TOT * CHK * 4);
    int* rangeBase = (int*)alloc(NB_TOT * 4);
    float* invCntM = (float*)alloc((size_t)NM_N * 4);
    float* invCntS = (float*)alloc((size_t)NS_N * 4);
    float* dinv0 = (float*)alloc((size_t)NM_N * 4);
    float* inv0  = (float*)alloc((size_t)NM_N * 4);
    float* dinv1 = (float*)alloc((size_t)NM_N * 4);
    float* inv1  = (float*)alloc((size_t)NM_N * 4);
    float* bsum  = (float*)alloc(256 * 4);
    int* csrA = (int*)alloc((size_t)E1_N * 4);
    int* csrS = (int*)alloc((size_t)E1_N * 4);
    int* csr0 = (int*)alloc((size_t)E2_N * 4);
    int* csr1 = (int*)alloc((size_t)E2_N * 4);
    unsigned short* emb_s16 = (unsigned short*)alloc((size_t)NS_N * HD * 2);
    unsigned short* emb_m16 = (unsigned short*)alloc((size_t)NM_N * HD * 2);
    unsigned short* Wt  = (unsigned short*)alloc((size_t)12 * HD * HD * 2);
    unsigned short* A   = (unsigned short*)alloc((size_t)NM_N * HD * 2);
    unsigned short* B0  = (unsigned short*)alloc((size_t)NM_N * HD * 2);
    unsigned short* B1  = (unsigned short*)alloc((size_t)NM_N * HD * 2);
    unsigned short* Sg  = (unsigned short*)alloc((size_t)NS_N * HD * 2);
    unsigned short* xma = (unsigned short*)alloc((size_t)NM_N * HD * 2);
    unsigned short* xsa = (unsigned short*)alloc((size_t)NS_N * HD * 2);

    count_conv<<<NCB + NCONV, 256, 0, stream>>>(e1s, e1d, e2s, e2d, subcnt, chunkTot,
                                                emb_s, emb_m, sage_Wl, sage_Wr, gcn_W,
                                                emb_s16, emb_m16, Wt);
    scan_ranges2<<<1, 64, 0, stream>>>(chunkTot, rangeBase);
    reduce_scan<<<NB_TOT, 1024, 0, stream>>>(rangeBase, subcnt,
                                             cntM, cntS, cnt0, cnt1,
                                             offM, offS, off0, off1);
    place_fin<<<NCB + NFIN, 256, 0, stream>>>(e1s, e1d, e2s, e2d, subcnt,
                                              csrA, csrS, csr0, csr1,
                                              cntM, cntS, cnt0, cnt1,
                                              invCntM, invCntS,
                                              dinv0, inv0, dinv1, inv1,
                                              sage_bl, gcn_b, bsum);

    for (int l = 0; l < 2; l++) {
        const unsigned short* xs_cur = l ? (const unsigned short*)xsa : emb_s16;
        const unsigned short* xm_cur = l ? (const unsigned short*)xma : emb_m16;
        gather_all<<<10000, 256, 0, stream>>>(xs_cur, xm_cur,
                                              csrA, offM, cntM, invCntM,
                                              csrS, offS, cntS, invCntS,
                                              csr0, off0, cnt0, dinv0, inv0,
                                              csr1, off1, cnt1, dinv1, inv1,
                                              A, Sg, B0, B1);
        gemm_all<<<470, 256, 0, stream>>>(A, xm_cur, B0, B1, Sg, xs_cur,
                                          Wt, bsum,
                                          sage_bl + (size_t)(l * 2 + 1) * HD,
                                          xma, xsa, l);
    }
    classify16<<<12500, 256, 0, stream>>>(xsa, xma, ls, ld, out);
}